// Round 6
// baseline (117.826 us; speedup 1.0000x reference)
//
#include <hip/hip_runtime.h>

typedef __attribute__((ext_vector_type(8))) short short8;
typedef __attribute__((ext_vector_type(4))) float f32x4;

#define C_DIM 128
#define K_CODES 1024
#define TOT 8388608   // 16*128*64*64
#define NBLK 512      // 128 contiguous pixels per block

__device__ __forceinline__ unsigned int f2bf1(float f) {
  unsigned int u = __float_as_uint(f);
  return (u + 0x7FFFu + ((u >> 16) & 1u)) >> 16;   // RNE fp32->bf16
}
__device__ __forceinline__ unsigned int f2bf2(float lo, float hi) {
  return f2bf1(lo) | (f2bf1(hi) << 16);
}

union U16x8 { uint4 u; short8 s; };

// ---- P: bf16 codebook + (1 + ||e||^2) + zero used ----
// Grid 128: 32768 threads x (16B read / 8B write) == K*C exactly (R8 lesson).
__global__ void prep_kernel(const float* __restrict__ cb,
                            unsigned short* __restrict__ ebf,
                            float* __restrict__ nsq1,
                            int* __restrict__ used) {
  int gid = blockIdx.x * 256 + threadIdx.x;     // 128 blocks * 256 = 32768 = K*C/4
  const float4 v = ((const float4*)cb)[gid];    // 32768*16B = 512KB = cb size
  uint2 pk;
  pk.x = f2bf2(v.x, v.y);
  pk.y = f2bf2(v.z, v.w);
  ((uint2*)ebf)[gid] = pk;                      // 32768*8B = 256KB = ebf size
  if (gid < K_CODES) {
    float s = 0.f;
    #pragma unroll 8
    for (int c = 0; c < C_DIM; ++c) { float w = cb[gid * C_DIM + c]; s += w * w; }
    nsq1[gid] = 1.0f + s;      // +1 keeps d positive -> u32-monotone float bits
    used[gid] = 0;
  }
}

// ---- M: block = 128 px; 8 waves = px-half (ph) x code-quarter (kq) ----
// R5 post-mortem: R11's 8-wave split (2 m-tiles/wave) halved MFMA-per-ds_read
// -> doubled LDS read traffic, cancelling the 2x occupancy gain (total parity
// with R0). LDS pipe is the wall: ~96-160 b128 instr/chunk/CU plus measured
// SQ_LDS_BANK_CONFLICT = 2.1M cyc/dispatch (~3.4us/CU) from the nL*4+q slot
// layout (16 lanes on 2 bank-quads).
// R12: (a) wave = 64 px x 256 codes (4 m-tiles x 1 jj) -> 4 MFMA per ds_read,
// 32 reads/chunk/block (R0 level) at 4 waves/SIMD; (b) bijective XOR swizzle
// slot = p*256+sks*64+(r>>1)*8+(((r^sks)&1)<<2)+((sq^(r>>1))&3): every 8-lane
// phase of reads (fixed g, r varies) AND writes (fixed r, g varies) covers 8
// distinct bank-quads -> conflict-free both sides (plain ds ops, rule-21 ok).
// Epilogue: R0 structure (plain used[]=1, lossp, separate finalize) — R3/R4
// proved in-kernel cross-XCD coherence costs ~us/block vs free kernel boundary.
// Math (verified R4-R6): A=bf16(-2z), MFMA C-init = 1+||e||^2 -> d directly;
// key=(bits(d)&~1023)|code, argmin via u32 min.
__global__ __launch_bounds__(512, 4)
void vq_main(const float* __restrict__ zin,
             const unsigned short* __restrict__ ebf,
             const float* __restrict__ nsq1,
             int* __restrict__ used, float* __restrict__ lossp,
             float* __restrict__ out) {
  __shared__ __align__(16) uint4 bG[2][1024];   // 2 x 16KB: 64-code chunks
  __shared__ float nsq_s[K_CODES];
  __shared__ unsigned int mergeK[128][4];
  __shared__ int   widx[128];
  __shared__ float wsum[8];

  const int t  = threadIdx.x;        // 0..511
  const int L  = t & 63;
  const int wv = t >> 6;             // wave 0..7
  const int ph = wv >> 2;            // pixel half: px [ph*64, ph*64+64)
  const int kq = wv & 3;             // code quarter: jj tile = kq
  const int q  = L >> 4;             // lane quad
  const int nL = L & 15;

  const int bb = blockIdx.x >> 5;          // batch 0..15
  const int hg = blockIdx.x & 31;          // 128-px group
  const int zoff = bb * (C_DIM * 4096) + hg * 128;   // + c*4096 + p

  for (int i = t; i < K_CODES; i += 512) nsq_s[i] = nsq1[i];

  // ---- A fragments straight from global, packed bf16(-2z) in-register
  // lane L, m-tile mt (0..3): pixel = ph*64 + mt*16 + nL, k = ks*32 + q*8 + u
  short8 afrag[16];
  #pragma unroll
  for (int mt = 0; mt < 4; ++mt) {
    const int wcol = ph * 64 + mt * 16 + nL;
    #pragma unroll
    for (int ks = 0; ks < 4; ++ks) {
      float v[8];
      #pragma unroll
      for (int u = 0; u < 8; ++u)
        v[u] = zin[zoff + (ks * 32 + q * 8 + u) * 4096 + wcol];
      U16x8 pk;
      pk.u.x = f2bf2(-2.f * v[0], -2.f * v[1]);
      pk.u.y = f2bf2(-2.f * v[2], -2.f * v[3]);
      pk.u.z = f2bf2(-2.f * v[4], -2.f * v[5]);
      pk.u.w = f2bf2(-2.f * v[6], -2.f * v[7]);
      afrag[mt * 4 + ks] = pk.s;
    }
  }

  // ---- staging thread roles: 512 threads x 2 granules = 1024 x 16B / chunk
  const uint4* __restrict__ ebv = (const uint4*)ebf;   // granule view, row=16
  const int nLw = (t >> 4) & 15;     // row-within-group
  const int oct = t & 15;            // granule-within-row
  const int pb  = t >> 8;            // 0..1 -> p = pb + 2*i
  const int sks = oct >> 2, sq = oct & 3;
  // swizzled LDS slot for (row r = p*16+nLw, granule g = oct):
  // sw_lo = (r>>1 & 7)*8 + (((r^g>>2)&1)<<2) + ((g&3 ^ (r>>1))&3); here
  // r low bits == nLw low bits (p*16 is 16-aligned).
  const int swbase = (nLw >> 1) * 8 + (((nLw ^ sks) & 1) << 2)
                   + ((sq ^ (nLw >> 1)) & 3);

  // stage chunk 0
  #pragma unroll
  for (int i = 0; i < 2; ++i) {
    int p = pb + 2 * i;                          // row-group within chunk
    bG[0][p * 256 + sks * 64 + swbase] = ebv[(p * 16 + nLw) * 16 + oct];
  }
  __syncthreads();

  // read-side swizzled slots (jj=kq fixed, ks varies; r low bits == nL):
  // sA for even ks, sB for odd ks (bit2 flips with ks&1)
  const int rdq = (q ^ (nL >> 1)) & 3;
  const int sA = kq * 256 + (nL >> 1) * 8 + (((nL) & 1) << 2) + rdq;
  const int sB = kq * 256 + (nL >> 1) * 8 + (((nL ^ 1) & 1) << 2) + rdq;

  unsigned int kmin[16];
  #pragma unroll
  for (int i = 0; i < 16; ++i) kmin[i] = 0xFFFFFFFFu;

  // ---- K loop: 16 chunks; this wave consumes its 1 jj-tile (16 codes)
  #pragma unroll 1
  for (int ch = 0; ch < 16; ++ch) {
    const int cur = ch & 1;
    if (ch < 15) {                               // stage next chunk into !cur
      #pragma unroll
      for (int i = 0; i < 2; ++i) {
        int p = pb + 2 * i;
        bG[cur ^ 1][p * 256 + sks * 64 + swbase] =
            ebv[((ch + 1) * 64 + p * 16 + nLw) * 16 + oct];
      }
    }
    const short8* bp = (const short8*)bG[cur];
    {
      const int row = ch * 64 + kq * 16 + nL;    // this lane's code (col nL)
      short8 b0 = bp[sA];            // ks=0
      short8 b1 = bp[sB + 64];       // ks=1
      short8 b2 = bp[sA + 128];      // ks=2
      short8 b3 = bp[sB + 192];      // ks=3
      const float nv = nsq_s[row];
      f32x4 c0 = {nv, nv, nv, nv};
      f32x4 c1 = {nv, nv, nv, nv};
      f32x4 c2 = {nv, nv, nv, nv};
      f32x4 c3 = {nv, nv, nv, nv};
      c0 = __builtin_amdgcn_mfma_f32_16x16x32_bf16(afrag[0],  b0, c0, 0, 0, 0);
      c1 = __builtin_amdgcn_mfma_f32_16x16x32_bf16(afrag[4],  b0, c1, 0, 0, 0);
      c2 = __builtin_amdgcn_mfma_f32_16x16x32_bf16(afrag[8],  b0, c2, 0, 0, 0);
      c3 = __builtin_amdgcn_mfma_f32_16x16x32_bf16(afrag[12], b0, c3, 0, 0, 0);
      c0 = __builtin_amdgcn_mfma_f32_16x16x32_bf16(afrag[1],  b1, c0, 0, 0, 0);
      c1 = __builtin_amdgcn_mfma_f32_16x16x32_bf16(afrag[5],  b1, c1, 0, 0, 0);
      c2 = __builtin_amdgcn_mfma_f32_16x16x32_bf16(afrag[9],  b1, c2, 0, 0, 0);
      c3 = __builtin_amdgcn_mfma_f32_16x16x32_bf16(afrag[13], b1, c3, 0, 0, 0);
      c0 = __builtin_amdgcn_mfma_f32_16x16x32_bf16(afrag[2],  b2, c0, 0, 0, 0);
      c1 = __builtin_amdgcn_mfma_f32_16x16x32_bf16(afrag[6],  b2, c1, 0, 0, 0);
      c2 = __builtin_amdgcn_mfma_f32_16x16x32_bf16(afrag[10], b2, c2, 0, 0, 0);
      c3 = __builtin_amdgcn_mfma_f32_16x16x32_bf16(afrag[14], b2, c3, 0, 0, 0);
      c0 = __builtin_amdgcn_mfma_f32_16x16x32_bf16(afrag[3],  b3, c0, 0, 0, 0);
      c1 = __builtin_amdgcn_mfma_f32_16x16x32_bf16(afrag[7],  b3, c1, 0, 0, 0);
      c2 = __builtin_amdgcn_mfma_f32_16x16x32_bf16(afrag[11], b3, c2, 0, 0, 0);
      c3 = __builtin_amdgcn_mfma_f32_16x16x32_bf16(afrag[15], b3, c3, 0, 0, 0);
      const unsigned int rowc = (unsigned int)row;
      #pragma unroll
      for (int r = 0; r < 4; ++r) {
        unsigned int k0 = (__float_as_uint(c0[r]) & 0xFFFFFC00u) | rowc;
        if (k0 < kmin[r]) kmin[r] = k0;
        unsigned int k1 = (__float_as_uint(c1[r]) & 0xFFFFFC00u) | rowc;
        if (k1 < kmin[4 + r]) kmin[4 + r] = k1;
        unsigned int k2 = (__float_as_uint(c2[r]) & 0xFFFFFC00u) | rowc;
        if (k2 < kmin[8 + r]) kmin[8 + r] = k2;
        unsigned int k3 = (__float_as_uint(c3[r]) & 0xFFFFFC00u) | rowc;
        if (k3 < kmin[12 + r]) kmin[12 + r] = k3;
      }
    }
    __syncthreads();   // next-chunk writes visible; cur free for re-stage
  }

  // ---- in-wave butterfly u32-min over the 16 code-lanes (nL bits)
  #pragma unroll
  for (int m = 1; m <= 8; m <<= 1) {
    #pragma unroll
    for (int i = 0; i < 16; ++i) {
      unsigned int o = (unsigned int)__shfl_xor((int)kmin[i], m, 64);
      if (o < kmin[i]) kmin[i] = o;
    }
  }
  if (nL == 0) {
    #pragma unroll
    for (int mt = 0; mt < 4; ++mt)
      #pragma unroll
      for (int r = 0; r < 4; ++r)
        mergeK[ph * 64 + mt * 16 + q * 4 + r][kq] = kmin[mt * 4 + r];
  }
  __syncthreads();

  // ---- cross-quarter merge (4-way u32 min per pixel); plain used store
  if (t < 128) {
    unsigned int b = min(min(mergeK[t][0], mergeK[t][1]),
                         min(mergeK[t][2], mergeK[t][3]));
    int bi = (int)(b & 1023u);
    widx[t] = bi;
    used[bi] = 1;   // benign same-value race; kernel boundary = coherence
  }
  __syncthreads();

  // ---- gather bf16 e-row + coalesced z/out + loss partial
  float lsum = 0.f;
  {
    const int p = t & 127, cg = t >> 7;    // 4 channel groups x 32 ch
    const int idx = widx[p];
    const uint4* erow = (const uint4*)ebf + idx * 16 + cg * 4;
    const int obase = zoff + cg * 32 * 4096 + p;
    #pragma unroll
    for (int i = 0; i < 4; ++i) {
      uint4 g = erow[i];
      const unsigned int wrd[4] = {g.x, g.y, g.z, g.w};
      #pragma unroll
      for (int half = 0; half < 4; ++half) {
        float e0 = __uint_as_float(wrd[half] << 16);
        float e1 = __uint_as_float(wrd[half] & 0xFFFF0000u);
        int off = obase + (i * 8 + half * 2) * 4096;
        float d0 = zin[off] - e0;
        out[off] = e0;                     // lanes over p -> 512B contiguous
        lsum += d0 * d0;
        off += 4096;
        float d1 = zin[off] - e1;
        out[off] = e1;
        lsum += d1 * d1;
      }
    }
  }
  #pragma unroll
  for (int o = 32; o > 0; o >>= 1) lsum += __shfl_down(lsum, o, 64);
  if (L == 0) wsum[wv] = lsum;
  __syncthreads();
  if (t == 0)
    lossp[blockIdx.x] = ((wsum[0] + wsum[1]) + (wsum[2] + wsum[3]))
                      + ((wsum[4] + wsum[5]) + (wsum[6] + wsum[7]));
}

// ---- F: usage count + loss finalize ----
__global__ void finalize_kernel(const int* __restrict__ used,
                                const float* __restrict__ lossp,
                                float* __restrict__ out2) {
  __shared__ int   redi[256];
  __shared__ float redf[256];
  int t = threadIdx.x;
  int s = 0;
  for (int i = t; i < K_CODES; i += 256) s += (used[i] != 0) ? 1 : 0;
  float ls = 0.f;
  for (int i = t; i < NBLK; i += 256) ls += lossp[i];
  redi[t] = s; redf[t] = ls;
  __syncthreads();
  for (int o = 128; o > 0; o >>= 1) {
    if (t < o) { redi[t] += redi[t + o]; redf[t] += redf[t + o]; }
    __syncthreads();
  }
  if (t == 0) {
    out2[0] = 1.25f * redf[0] / (float)TOT;  // (1+0.25)*MSE
    out2[1] = (float)redi[0] / 1024.0f;
  }
}

extern "C" void kernel_launch(void* const* d_in, const int* in_sizes, int n_in,
                              void* d_out, int out_size, void* d_ws, size_t ws_size,
                              hipStream_t stream) {
  const float* z  = (const float*)d_in[0];
  const float* cb = (const float*)d_in[1];
  float* out = (float*)d_out;
  char* ws = (char*)d_ws;
  unsigned short* ebf = (unsigned short*)ws;          // 262144 B
  float* nsq1  = (float*)(ws + 262144);               // 4096 B
  int*   used  = (int*)(ws + 266240);                 // 4096 B
  float* lossp = (float*)(ws + 270336);               // 2048 B (per-block partials)

  hipLaunchKernelGGL(prep_kernel, dim3(128), dim3(256), 0, stream,
                     cb, ebf, nsq1, used);
  hipLaunchKernelGGL(vq_main, dim3(NBLK), dim3(512), 0, stream,
                     z, ebf, nsq1, used, lossp, out);
  hipLaunchKernelGGL(finalize_kernel, dim3(1), dim3(256), 0, stream,
                     used, lossp, out + TOT);
}